// Round 4
// baseline (167.012 us; speedup 1.0000x reference)
//
#include <hip/hip_runtime.h>
#include <math.h>

#define B_ 16
#define D_ 128
#define HH 48
#define WW 48
#define N_ 2304
#define NC 72            // N_/32 column/row chunks
#define SCALE_ 16.0f
#define INV_TEMP 14.285714285714286f
#define L2E_TEMP 20.60992915555662f   // INV_TEMP * log2(e)
#define EPS_ 1e-8f
#define SPLIT 8
#define JC_PER 9         // NC/SPLIT

typedef __attribute__((ext_vector_type(8))) short bf16x8;
typedef __attribute__((ext_vector_type(16))) float f32x16;

__device__ __forceinline__ short f2bf(float f) {
    union { float f; unsigned u; } v; v.f = f;
    unsigned r = v.u + 0x7FFFu + ((v.u >> 16) & 1u);
    return (short)(r >> 16);
}

// fragment-major offset: chunk c of batch b, k-step ks, lane l, 8 bf16 elems
__device__ __forceinline__ size_t frag_off(int b, int c, int ks, int lane) {
    return ((((size_t)b * NC + c) * 8 + ks) << 9) + (size_t)lane * 8;
}

// ---------------- K1: warp + normalize -> bf16 fragment-major (A and B operands)
__global__ __launch_bounds__(256) void k_prep(const float* __restrict__ fa,
                                              const float* __restrict__ fb,
                                              const float* __restrict__ Ha,
                                              const float* __restrict__ Hb,
                                              const float* __restrict__ Mab,
                                              float* __restrict__ maskA,
                                              short* __restrict__ faF,
                                              short* __restrict__ wbF) {
    __shared__ float sbA[D_][33];    // d-major fp32: conflict-free writes & reads
    __shared__ float sbW[D_][33];
    __shared__ float part[8][2][32];
    __shared__ float rn[2][32];
    const int b = blockIdx.y;
    const int rb = blockIdx.x;       // 32-pixel chunk index (0..71)
    const int n0 = rb * 32;
    const int tid = threadIdx.x;
    const int nl = tid & 31, dg = tid >> 5;
    const int n = n0 + nl;

    // per-batch transform T = S_inv @ Hb @ M3 @ inv(Ha) @ S (redundant per thread)
    float T[9];
    {
        const float* A = Ha + b * 9;
        const float* Bm = Hb + b * 9;
        float c00 = A[4] * A[8] - A[5] * A[7];
        float c01 = A[5] * A[6] - A[3] * A[8];
        float c02 = A[3] * A[7] - A[4] * A[6];
        float id = 1.f / (A[0] * c00 + A[1] * c01 + A[2] * c02);
        float inv[9] = { c00 * id, (A[2] * A[7] - A[1] * A[8]) * id, (A[1] * A[5] - A[2] * A[4]) * id,
                         c01 * id, (A[0] * A[8] - A[2] * A[6]) * id, (A[2] * A[3] - A[0] * A[5]) * id,
                         c02 * id, (A[1] * A[6] - A[0] * A[7]) * id, (A[0] * A[4] - A[1] * A[3]) * id };
        float M3[9] = {Mab[0], Mab[1], Mab[2], Mab[3], Mab[4], Mab[5], 0.f, 0.f, 1.f};
        float P1[9], P2[9];
        for (int i = 0; i < 3; ++i)
            for (int j = 0; j < 3; ++j) {
                float s = 0.f;
                for (int k = 0; k < 3; ++k) s += Bm[i * 3 + k] * M3[k * 3 + j];
                P1[i * 3 + j] = s;
            }
        for (int i = 0; i < 3; ++i)
            for (int j = 0; j < 3; ++j) {
                float s = 0.f;
                for (int k = 0; k < 3; ++k) s += P1[i * 3 + k] * inv[k * 3 + j];
                P2[i * 3 + j] = s;
            }
        const float sc[3] = {SCALE_, SCALE_, 1.f};
        for (int i = 0; i < 3; ++i)
            for (int j = 0; j < 3; ++j) T[i * 3 + j] = P2[i * 3 + j] * sc[j] / sc[i];
    }

    const float gx = (float)(n % WW), gy = (float)(n / WW);
    const float X = T[0] * gx + T[1] * gy + T[2];
    const float Y = T[3] * gx + T[4] * gy + T[5];
    const float z = T[6] * gx + T[7] * gy + T[8] + EPS_;
    const float xn = 2.f * (X / z) / (float)(WW - 1) - 1.f;
    const float yn = 2.f * (Y / z) / (float)(HH - 1) - 1.f;
    const float msk = (xn >= -1.f && xn <= 1.f && yn >= -1.f && yn <= 1.f) ? 1.f : 0.f;
    const float ix = (xn + 1.f) * 0.5f * (float)(WW - 1);
    const float iy = (yn + 1.f) * 0.5f * (float)(HH - 1);
    const float x0f = floorf(ix), y0f = floorf(iy);
    const float wx1 = ix - x0f, wx0 = 1.f - wx1;
    const float wy1 = iy - y0f, wy0 = 1.f - wy1;
    const bool vx0 = (x0f >= 0.f) && (x0f <= 47.f);
    const bool vx1 = (x0f + 1.f >= 0.f) && (x0f + 1.f <= 47.f);
    const bool vy0 = (y0f >= 0.f) && (y0f <= 47.f);
    const bool vy1 = (y0f + 1.f >= 0.f) && (y0f + 1.f <= 47.f);
    const float w00 = (vx0 && vy0) ? wx0 * wy0 : 0.f;
    const float w01 = (vx1 && vy0) ? wx1 * wy0 : 0.f;
    const float w10 = (vx0 && vy1) ? wx0 * wy1 : 0.f;
    const float w11 = (vx1 && vy1) ? wx1 * wy1 : 0.f;
    const int x0c = (int)fminf(fmaxf(x0f, 0.f), 47.f);
    const int x1c = (int)fminf(fmaxf(x0f + 1.f, 0.f), 47.f);
    const int y0c = (int)fminf(fmaxf(y0f, 0.f), 47.f);
    const int y1c = (int)fminf(fmaxf(y0f + 1.f, 0.f), 47.f);
    const int o00 = y0c * WW + x0c, o01 = y0c * WW + x1c;
    const int o10 = y1c * WW + x0c, o11 = y1c * WW + x1c;

    const float* fab = fa + (size_t)b * D_ * N_;
    const float* fbb = fb + (size_t)b * D_ * N_;
    float sA = 0.f, sW = 0.f;
    for (int dd = 0; dd < 16; ++dd) {
        int d = dg * 16 + dd;
        const float* p = fbb + (size_t)d * N_;
        float w = w00 * p[o00] + w01 * p[o01] + w10 * p[o10] + w11 * p[o11];
        float a = fab[(size_t)d * N_ + n];     // coalesced across lanes
        sbA[d][nl] = a;
        sbW[d][nl] = w;
        sA += a * a;
        sW += w * w;
    }
    part[dg][0][nl] = sA;
    part[dg][1][nl] = sW;
    __syncthreads();
    if (tid < 32) {
        float ta = 0.f, tw = 0.f;
        for (int g = 0; g < 8; ++g) { ta += part[g][0][tid]; tw += part[g][1][tid]; }
        rn[0][tid] = 1.f / fmaxf(sqrtf(ta), 1e-12f);
        rn[1][tid] = 1.f / fmaxf(sqrtf(tw), 1e-12f);
        maskA[b * N_ + n0 + tid] = msk;   // tid<32 -> dg==0 -> own pixel's msk
    }
    __syncthreads();
    // pack phase: lane l = r + 32*h; wave w writes ks = w, w+4 -> fully coalesced 1KB stores
    const int lane = tid & 63, wv = tid >> 6;
    const int r = lane & 31, h = lane >> 5;
    const float sa = rn[0][r], sw = rn[1][r];
    for (int t = 0; t < 2; ++t) {
        const int ks = wv + t * 4;
        bf16x8 oa, ow;
        for (int j = 0; j < 8; ++j) {
            int d = ks * 16 + h * 8 + j;
            oa[j] = f2bf(sbA[d][r] * sa);
            ow[j] = f2bf(sbW[d][r] * sw);
        }
        size_t off = frag_off(b, rb, ks, lane);
        *(bf16x8*)(faF + off) = oa;
        *(bf16x8*)(wbF + off) = ow;
    }
}

// ---------------- K2: LDS-free, barrier-free MFMA K-loop (fragments straight from L2)
__global__ __launch_bounds__(256, 2) void k_loss(const short* __restrict__ faF,
                                                 const short* __restrict__ wbF,
                                                 float* __restrict__ Zpart,
                                                 float* __restrict__ dgbuf) {
    __shared__ float s_Z[256];
    const int bx = blockIdx.x;       // 0..8 (256 rows each)
    const int cs = blockIdx.y;       // column split 0..7
    const int b = blockIdx.z;
    const int tid = threadIdx.x;
    const int lane = tid & 63, wv = tid >> 6;
    const int l31 = lane & 31, h = lane >> 5;
    const int rc0 = bx * 8 + wv * 2, rc1 = rc0 + 1;   // this wave's two 32-row chunks

    bf16x8 a0[8], a1[8];
    #pragma unroll
    for (int ks = 0; ks < 8; ++ks) {
        a0[ks] = *(const bf16x8*)(faF + frag_off(b, rc0, ks, lane));
        a1[ks] = *(const bf16x8*)(faF + frag_off(b, rc1, ks, lane));
    }
    float Z0[16], Z1[16];
    #pragma unroll
    for (int i = 0; i < 16; ++i) { Z0[i] = 0.f; Z1[i] = 0.f; }

    for (int q = 0; q < JC_PER; ++q) {
        const int jc = cs * JC_PER + q;
        const short* bbase = wbF + frag_off(b, jc, 0, lane);
        f32x16 C0, C1;
        #pragma unroll
        for (int i = 0; i < 16; ++i) { C0[i] = 0.f; C1[i] = 0.f; }
        #pragma unroll
        for (int ks = 0; ks < 8; ++ks) {
            bf16x8 bf = *(const bf16x8*)(bbase + ks * 512);
            C0 = __builtin_amdgcn_mfma_f32_32x32x16_bf16(a0[ks], bf, C0, 0, 0, 0);
            C1 = __builtin_amdgcn_mfma_f32_32x32x16_bf16(a1[ks], bf, C1, 0, 0, 0);
        }
        #pragma unroll
        for (int i = 0; i < 16; ++i) {
            Z0[i] += exp2f(fmaf(C0[i], L2E_TEMP, -L2E_TEMP));
            Z1[i] += exp2f(fmaf(C1[i], L2E_TEMP, -L2E_TEMP));
        }
        if (jc == rc0) {   // diagonal tile for row set 0 (unique writer)
            #pragma unroll
            for (int i = 0; i < 16; ++i) {
                int rl = (i & 3) + 8 * (i >> 2) + 4 * h;
                if (l31 == rl) dgbuf[b * N_ + rc0 * 32 + rl] = INV_TEMP * C0[i];
            }
        }
        if (jc == rc1) {
            #pragma unroll
            for (int i = 0; i < 16; ++i) {
                int rl = (i & 3) + 8 * (i >> 2) + 4 * h;
                if (l31 == rl) dgbuf[b * N_ + rc1 * 32 + rl] = INV_TEMP * C1[i];
            }
        }
    }
    // reduce over the 32 column lanes (stays within each h-half)
    #pragma unroll
    for (int i = 0; i < 16; ++i) {
        float z0 = Z0[i], z1 = Z1[i];
        z0 += __shfl_xor(z0, 1);  z1 += __shfl_xor(z1, 1);
        z0 += __shfl_xor(z0, 2);  z1 += __shfl_xor(z1, 2);
        z0 += __shfl_xor(z0, 4);  z1 += __shfl_xor(z1, 4);
        z0 += __shfl_xor(z0, 8);  z1 += __shfl_xor(z1, 8);
        z0 += __shfl_xor(z0, 16); z1 += __shfl_xor(z1, 16);
        Z0[i] = z0; Z1[i] = z1;
    }
    if (l31 == 0) {   // lanes 0 and 32: rows disjoint per wave -> plain stores
        #pragma unroll
        for (int i = 0; i < 16; ++i) {
            int rl = (i & 3) + 8 * (i >> 2) + 4 * h;
            s_Z[wv * 64 + rl] = Z0[i];
            s_Z[wv * 64 + 32 + rl] = Z1[i];
        }
    }
    __syncthreads();
    Zpart[((size_t)cs * B_ + b) * N_ + bx * 256 + tid] = s_Z[tid];
}

// ---------------- K3: per-row loss + masked reduction
__global__ __launch_bounds__(256) void k_pass2(const float* __restrict__ maskA,
                                               const float* __restrict__ Zpart,
                                               const float* __restrict__ dgbuf,
                                               float* __restrict__ acc) {
    const int idx = blockIdx.x * 256 + threadIdx.x;   // B_*N_ = 144*256
    float Zs = 0.f;
    for (int s = 0; s < SPLIT; ++s) Zs += Zpart[(size_t)s * B_ * N_ + idx];
    const float m = maskA[idx];
    float lossv = (logf(Zs) + INV_TEMP - dgbuf[idx]) * m;
    float cm = m;
    for (int off = 1; off < 64; off <<= 1) {
        lossv += __shfl_xor(lossv, off);
        cm += __shfl_xor(cm, off);
    }
    __shared__ float s[8];
    const int wv = threadIdx.x >> 6;
    if ((threadIdx.x & 63) == 0) { s[wv * 2] = lossv; s[wv * 2 + 1] = cm; }
    __syncthreads();
    if (threadIdx.x == 0) {
        atomicAdd(&acc[0], s[0] + s[2] + s[4] + s[6]);
        atomicAdd(&acc[1], s[1] + s[3] + s[5] + s[7]);
    }
}

// ---------------- K4: finalize
__global__ void k_final(const float* __restrict__ acc, float* __restrict__ out) {
    float t = acc[0], c = acc[1];
    out[0] = (c > 0.f) ? t / fmaxf(c, 1.f) : 0.f;
}

extern "C" void kernel_launch(void* const* d_in, const int* in_sizes, int n_in,
                              void* d_out, int out_size, void* d_ws, size_t ws_size,
                              hipStream_t stream) {
    const float* fa = (const float*)d_in[0];
    const float* fb = (const float*)d_in[1];
    const float* Ha = (const float*)d_in[2];
    const float* Hb = (const float*)d_in[3];
    const float* M = (const float*)d_in[4];
    float* out = (float*)d_out;

    float* wsf = (float*)d_ws;
    float* accp = wsf;                              // 2 floats
    float* maskA = wsf + 2;                         // B*N
    float* dgbuf = maskA + B_ * N_;                 // B*N (fully written)
    float* Zpart = dgbuf + B_ * N_;                 // SPLIT*B*N (fully written)
    short* faF = (short*)(Zpart + (size_t)SPLIT * B_ * N_);   // B*NC*8*512 bf16
    short* wbF = faF + (size_t)B_ * NC * 8 * 512;

    hipMemsetAsync(accp, 0, 2 * sizeof(float), stream);
    hipLaunchKernelGGL(k_prep, dim3(NC, B_), dim3(256), 0, stream,
                       fa, fb, Ha, Hb, M, maskA, faF, wbF);
    hipLaunchKernelGGL(k_loss, dim3(9, SPLIT, B_), dim3(256), 0, stream,
                       faF, wbF, Zpart, dgbuf);
    hipLaunchKernelGGL(k_pass2, dim3(B_ * N_ / 256), dim3(256), 0, stream,
                       maskA, Zpart, dgbuf, accp);
    hipLaunchKernelGGL(k_final, dim3(1), dim3(1), 0, stream, accp, out);
}

// Round 5
// 138.866 us; speedup vs baseline: 1.2027x; 1.2027x over previous
//
#include <hip/hip_runtime.h>
#include <math.h>

#define B_ 16
#define D_ 128
#define HH 48
#define WW 48
#define N_ 2304
#define NC 72            // N_/32 row/col chunks of 32
#define SCALE_ 16.0f
#define INV_TEMP 14.285714285714286f
#define L2E_TEMP 20.60992915555662f   // INV_TEMP * log2(e)
#define EPS_ 1e-8f
#define SPLITC 6
#define STAGES 6         // per block: 6 stages x 64 cols = 384 cols = N_/SPLITC

typedef __attribute__((ext_vector_type(8))) short bf16x8;
typedef __attribute__((ext_vector_type(16))) float f32x16;

__device__ __forceinline__ short f2bf(float f) {
    union { float f; unsigned u; } v; v.f = f;
    unsigned r = v.u + 0x7FFFu + ((v.u >> 16) & 1u);
    return (short)(r >> 16);
}

// fragment-major offset (shorts): chunk c (32 rows/cols), k-step ks, lane l, 8 bf16
__device__ __forceinline__ size_t frag_off(int b, int c, int ks, int lane) {
    return ((((size_t)b * NC + c) * 8 + ks) << 9) + (size_t)lane * 8;
}

// ---------------- K1: warp + normalize -> bf16 fragment-major; transpose-free
// Each thread gathers exactly the 16 d-values its output fragments need.
__global__ __launch_bounds__(256) void k_prep(const float* __restrict__ fa,
                                              const float* __restrict__ fb,
                                              const float* __restrict__ Ha,
                                              const float* __restrict__ Hb,
                                              const float* __restrict__ Mab,
                                              float* __restrict__ maskA,
                                              short* __restrict__ faF,
                                              short* __restrict__ wbF) {
    __shared__ float part[4][2][32];
    const int b = blockIdx.y;
    const int rb = blockIdx.x;          // 32-pixel chunk (0..71)
    const int n0 = rb * 32;
    const int tid = threadIdx.x;
    const int lane = tid & 63, wv = tid >> 6;
    const int r = lane & 31, h = lane >> 5;
    const int n = n0 + r;

    // per-batch transform T = S_inv @ Hb @ M3 @ inv(Ha) @ S (redundant per thread)
    float T[9];
    {
        const float* A = Ha + b * 9;
        const float* Bm = Hb + b * 9;
        float c00 = A[4] * A[8] - A[5] * A[7];
        float c01 = A[5] * A[6] - A[3] * A[8];
        float c02 = A[3] * A[7] - A[4] * A[6];
        float id = 1.f / (A[0] * c00 + A[1] * c01 + A[2] * c02);
        float inv[9] = { c00 * id, (A[2] * A[7] - A[1] * A[8]) * id, (A[1] * A[5] - A[2] * A[4]) * id,
                         c01 * id, (A[0] * A[8] - A[2] * A[6]) * id, (A[2] * A[3] - A[0] * A[5]) * id,
                         c02 * id, (A[1] * A[6] - A[0] * A[7]) * id, (A[0] * A[4] - A[1] * A[3]) * id };
        float M3[9] = {Mab[0], Mab[1], Mab[2], Mab[3], Mab[4], Mab[5], 0.f, 0.f, 1.f};
        float P1[9], P2[9];
        for (int i = 0; i < 3; ++i)
            for (int j = 0; j < 3; ++j) {
                float s = 0.f;
                for (int k = 0; k < 3; ++k) s += Bm[i * 3 + k] * M3[k * 3 + j];
                P1[i * 3 + j] = s;
            }
        for (int i = 0; i < 3; ++i)
            for (int j = 0; j < 3; ++j) {
                float s = 0.f;
                for (int k = 0; k < 3; ++k) s += P1[i * 3 + k] * inv[k * 3 + j];
                P2[i * 3 + j] = s;
            }
        const float sc[3] = {SCALE_, SCALE_, 1.f};
        for (int i = 0; i < 3; ++i)
            for (int j = 0; j < 3; ++j) T[i * 3 + j] = P2[i * 3 + j] * sc[j] / sc[i];
    }

    const float gx = (float)(n % WW), gy = (float)(n / WW);
    const float X = T[0] * gx + T[1] * gy + T[2];
    const float Y = T[3] * gx + T[4] * gy + T[5];
    const float z = T[6] * gx + T[7] * gy + T[8] + EPS_;
    const float xn = 2.f * (X / z) / (float)(WW - 1) - 1.f;
    const float yn = 2.f * (Y / z) / (float)(HH - 1) - 1.f;
    const float msk = (xn >= -1.f && xn <= 1.f && yn >= -1.f && yn <= 1.f) ? 1.f : 0.f;
    const float ix = (xn + 1.f) * 0.5f * (float)(WW - 1);
    const float iy = (yn + 1.f) * 0.5f * (float)(HH - 1);
    const float x0f = floorf(ix), y0f = floorf(iy);
    const float wx1 = ix - x0f, wx0 = 1.f - wx1;
    const float wy1 = iy - y0f, wy0 = 1.f - wy1;
    const bool vx0 = (x0f >= 0.f) && (x0f <= 47.f);
    const bool vx1 = (x0f + 1.f >= 0.f) && (x0f + 1.f <= 47.f);
    const bool vy0 = (y0f >= 0.f) && (y0f <= 47.f);
    const bool vy1 = (y0f + 1.f >= 0.f) && (y0f + 1.f <= 47.f);
    const float w00 = (vx0 && vy0) ? wx0 * wy0 : 0.f;
    const float w01 = (vx1 && vy0) ? wx1 * wy0 : 0.f;
    const float w10 = (vx0 && vy1) ? wx0 * wy1 : 0.f;
    const float w11 = (vx1 && vy1) ? wx1 * wy1 : 0.f;
    const int x0c = (int)fminf(fmaxf(x0f, 0.f), 47.f);
    const int x1c = (int)fminf(fmaxf(x0f + 1.f, 0.f), 47.f);
    const int y0c = (int)fminf(fmaxf(y0f, 0.f), 47.f);
    const int y1c = (int)fminf(fmaxf(y0f + 1.f, 0.f), 47.f);
    const int o00 = y0c * WW + x0c, o01 = y0c * WW + x1c;
    const int o10 = y1c * WW + x0c, o11 = y1c * WW + x1c;

    const float* fab = fa + (size_t)b * D_ * N_;
    const float* fbb = fb + (size_t)b * D_ * N_;

    float av[2][8], wvv[2][8];
    float sA = 0.f, sW = 0.f;
    #pragma unroll
    for (int g = 0; g < 2; ++g) {
        const int ks = wv + 4 * g;
        const int dbase = ks * 16 + h * 8;
        #pragma unroll
        for (int j = 0; j < 8; ++j) {
            const int d = dbase + j;
            const float* p = fbb + (size_t)d * N_;
            float w = w00 * p[o00] + w01 * p[o01] + w10 * p[o10] + w11 * p[o11];
            float a = fab[(size_t)d * N_ + n];     // 2x128B segments per wave-load
            av[g][j] = a; wvv[g][j] = w;
            sA += a * a; sW += w * w;
        }
    }
    // norm: combine h-halves then waves
    sA += __shfl_xor(sA, 32);
    sW += __shfl_xor(sW, 32);
    if (lane < 32) { part[wv][0][r] = sA; part[wv][1][r] = sW; }
    if (tid < 32) maskA[b * N_ + n0 + r] = msk;
    __syncthreads();
    const float rnA = 1.f / fmaxf(sqrtf(part[0][0][r] + part[1][0][r] + part[2][0][r] + part[3][0][r]), 1e-12f);
    const float rnW = 1.f / fmaxf(sqrtf(part[0][1][r] + part[1][1][r] + part[2][1][r] + part[3][1][r]), 1e-12f);

    #pragma unroll
    for (int g = 0; g < 2; ++g) {
        const int ks = wv + 4 * g;
        bf16x8 oa, ow;
        #pragma unroll
        for (int j = 0; j < 8; ++j) {
            oa[j] = f2bf(av[g][j] * rnA);
            ow[j] = f2bf(wvv[g][j] * rnW);
        }
        size_t off = frag_off(b, rb, ks, lane);
        *(bf16x8*)(faF + off) = oa;     // 1KB coalesced store per wave
        *(bf16x8*)(wbF + off) = ow;
    }
}

// ---------------- K2: MFMA logits; A-frags in regs, B double-buffered through LDS
__global__ __launch_bounds__(256, 4) void k_loss(const short* __restrict__ faF,
                                                 const short* __restrict__ wbF,
                                                 float* __restrict__ Zpart,
                                                 float* __restrict__ dgbuf) {
    __shared__ short bbuf[2][8192];   // 2 x 16 KB stage (64 cols x 128 k bf16, frag-major)
    __shared__ float s_Z[128];
    const int bx = blockIdx.x;        // row block: 128 rows
    const int cs = blockIdx.y;        // col split: 384 cols
    const int b = blockIdx.z;
    const int tid = threadIdx.x;
    const int lane = tid & 63, w = tid >> 6;
    const int l31 = lane & 31, h = lane >> 5;
    const int rc = bx * 4 + w;        // this wave's 32-row chunk

    bf16x8 af[8];
    #pragma unroll
    for (int ks = 0; ks < 8; ++ks)
        af[ks] = *(const bf16x8*)(faF + frag_off(b, rc, ks, lane));

    float Z[16];
    #pragma unroll
    for (int i = 0; i < 16; ++i) Z[i] = 0.f;

    const short* bsrc = wbF + frag_off(b, cs * 12, 0, 0);   // 12 chunks = 6 stages x 8192 shorts

    // prologue: stage 0 -> bbuf[0]
    #pragma unroll
    for (int i = 0; i < 4; ++i)
        *(float4*)(&bbuf[0][tid * 8 + i * 2048]) = *(const float4*)(bsrc + tid * 8 + i * 2048);
    __syncthreads();

    for (int s = 0; s < STAGES; ++s) {
        float4 pf[4];
        const bool more = (s + 1 < STAGES);
        if (more) {
            const short* src = bsrc + (s + 1) * 8192;
            #pragma unroll
            for (int i = 0; i < 4; ++i) pf[i] = *(const float4*)(src + tid * 8 + i * 2048);
        }
        const short* bb = &bbuf[s & 1][0];
        f32x16 C0, C1;
        #pragma unroll
        for (int i = 0; i < 16; ++i) { C0[i] = 0.f; C1[i] = 0.f; }
        #pragma unroll
        for (int ks = 0; ks < 8; ++ks) {
            bf16x8 b0 = *(const bf16x8*)(bb + ks * 512 + lane * 8);
            bf16x8 b1 = *(const bf16x8*)(bb + 4096 + ks * 512 + lane * 8);
            C0 = __builtin_amdgcn_mfma_f32_32x32x16_bf16(af[ks], b0, C0, 0, 0, 0);
            C1 = __builtin_amdgcn_mfma_f32_32x32x16_bf16(af[ks], b1, C1, 0, 0, 0);
        }
        #pragma unroll
        for (int i = 0; i < 16; ++i) {
            Z[i] += exp2f(fmaf(C0[i], L2E_TEMP, -L2E_TEMP))
                  + exp2f(fmaf(C1[i], L2E_TEMP, -L2E_TEMP));
        }
        const int jc0 = cs * 12 + 2 * s, jc1 = jc0 + 1;
        if (jc0 == rc) {          // wave-uniform; unique diag owner
            #pragma unroll
            for (int i = 0; i < 16; ++i) {
                int rr = (i & 3) + 8 * (i >> 2) + 4 * h;
                if (l31 == rr) dgbuf[b * N_ + rc * 32 + rr] = INV_TEMP * C0[i];
            }
        }
        if (jc1 == rc) {
            #pragma unroll
            for (int i = 0; i < 16; ++i) {
                int rr = (i & 3) + 8 * (i >> 2) + 4 * h;
                if (l31 == rr) dgbuf[b * N_ + rc * 32 + rr] = INV_TEMP * C1[i];
            }
        }
        if (more) {
            short* dst = &bbuf[(s + 1) & 1][0];
            #pragma unroll
            for (int i = 0; i < 4; ++i) *(float4*)(dst + tid * 8 + i * 2048) = pf[i];
        }
        __syncthreads();
    }

    // reduce Z over 32 column lanes (stays within h-half)
    #pragma unroll
    for (int i = 0; i < 16; ++i) {
        float z = Z[i];
        z += __shfl_xor(z, 1);
        z += __shfl_xor(z, 2);
        z += __shfl_xor(z, 4);
        z += __shfl_xor(z, 8);
        z += __shfl_xor(z, 16);
        if (l31 == 0) {
            int rr = (i & 3) + 8 * (i >> 2) + 4 * h;
            s_Z[w * 32 + rr] = z;
        }
    }
    __syncthreads();
    if (tid < 128)
        Zpart[((size_t)cs * B_ + b) * N_ + bx * 128 + tid] = s_Z[tid];
}

// ---------------- K3: per-row loss + per-block partial sums (no atomics)
__global__ __launch_bounds__(256) void k_pass2(const float* __restrict__ maskA,
                                               const float* __restrict__ Zpart,
                                               const float* __restrict__ dgbuf,
                                               float* __restrict__ partials) {
    const int idx = blockIdx.x * 256 + threadIdx.x;   // B_*N_ = 144*256
    float Zs = 0.f;
    #pragma unroll
    for (int s = 0; s < SPLITC; ++s) Zs += Zpart[(size_t)s * B_ * N_ + idx];
    const float m = maskA[idx];
    float lossv = (logf(Zs) + INV_TEMP - dgbuf[idx]) * m;
    float cm = m;
    for (int off = 1; off < 64; off <<= 1) {
        lossv += __shfl_xor(lossv, off);
        cm += __shfl_xor(cm, off);
    }
    __shared__ float s[8];
    const int wv = threadIdx.x >> 6;
    if ((threadIdx.x & 63) == 0) { s[wv * 2] = lossv; s[wv * 2 + 1] = cm; }
    __syncthreads();
    if (threadIdx.x == 0) {
        partials[blockIdx.x * 2] = s[0] + s[2] + s[4] + s[6];
        partials[blockIdx.x * 2 + 1] = s[1] + s[3] + s[5] + s[7];
    }
}

// ---------------- K4: final reduce of 144 partials
__global__ void k_final(const float* __restrict__ partials, float* __restrict__ out) {
    const int t = threadIdx.x;   // 64 threads
    float tt = 0.f, cc = 0.f;
    for (int i = t; i < 144; i += 64) { tt += partials[i * 2]; cc += partials[i * 2 + 1]; }
    for (int off = 1; off < 64; off <<= 1) {
        tt += __shfl_xor(tt, off);
        cc += __shfl_xor(cc, off);
    }
    if (t == 0) out[0] = (cc > 0.f) ? tt / fmaxf(cc, 1.f) : 0.f;
}

extern "C" void kernel_launch(void* const* d_in, const int* in_sizes, int n_in,
                              void* d_out, int out_size, void* d_ws, size_t ws_size,
                              hipStream_t stream) {
    const float* fa = (const float*)d_in[0];
    const float* fb = (const float*)d_in[1];
    const float* Ha = (const float*)d_in[2];
    const float* Hb = (const float*)d_in[3];
    const float* M = (const float*)d_in[4];
    float* out = (float*)d_out;

    float* wsf = (float*)d_ws;
    float* Zpart = wsf;                                   // SPLITC*B*N (fully written)
    float* dgbuf = Zpart + (size_t)SPLITC * B_ * N_;      // B*N (fully written)
    float* maskA = dgbuf + B_ * N_;                       // B*N
    float* partials = maskA + B_ * N_;                    // 288
    short* faF = (short*)(partials + 512);                // B*NC*8*512 bf16
    short* wbF = faF + (size_t)B_ * NC * 8 * 512;

    hipLaunchKernelGGL(k_prep, dim3(NC, B_), dim3(256), 0, stream,
                       fa, fb, Ha, Hb, M, maskA, faF, wbF);
    hipLaunchKernelGGL(k_loss, dim3(N_ / 128, SPLITC, B_), dim3(256), 0, stream,
                       faF, wbF, Zpart, dgbuf);
    hipLaunchKernelGGL(k_pass2, dim3(B_ * N_ / 256), dim3(256), 0, stream,
                       maskA, Zpart, dgbuf, partials);
    hipLaunchKernelGGL(k_final, dim3(1), dim3(64), 0, stream, partials, out);
}